// Round 14
// baseline (568.598 us; speedup 1.0000x reference)
//
#include <hip/hip_runtime.h>
#include <hip/hip_bf16.h>

#define B_   128
#define S_   128
#define IN_  512
#define H_   256
#define G3_  768   // 3*H
#define C_   256
#define D2H_ 512   // 2*H

typedef short bf16x8 __attribute__((ext_vector_type(8)));
typedef float f32x4  __attribute__((ext_vector_type(4)));

static __device__ __forceinline__ short f2bf(float f) {
  unsigned u = __float_as_uint(f);
  return (short)((u + 0x7fffu + ((u >> 16) & 1u)) >> 16);
}
static __device__ __forceinline__ float bf2f(unsigned short v) {
  return __uint_as_float((unsigned)v << 16);
}

// async global->LDS, 16B per lane (LDS dest wave-uniform base, HW adds lane*16)
static __device__ __forceinline__ void async16(const void* g, const void* l) {
  __builtin_amdgcn_global_load_lds(
      (const __attribute__((address_space(1))) void*)g,
      (__attribute__((address_space(3))) void*)l, 16, 0, 0);
}

// full AGPR clobber list: any asm carrying this prevents the allocator from
// placing ANY value live across it into a0..a255.
#define AGPR_CLOB \
  "a0","a1","a2","a3","a4","a5","a6","a7","a8","a9",\
  "a10","a11","a12","a13","a14","a15","a16","a17","a18","a19",\
  "a20","a21","a22","a23","a24","a25","a26","a27","a28","a29",\
  "a30","a31","a32","a33","a34","a35","a36","a37","a38","a39",\
  "a40","a41","a42","a43","a44","a45","a46","a47","a48","a49",\
  "a50","a51","a52","a53","a54","a55","a56","a57","a58","a59",\
  "a60","a61","a62","a63","a64","a65","a66","a67","a68","a69",\
  "a70","a71","a72","a73","a74","a75","a76","a77","a78","a79",\
  "a80","a81","a82","a83","a84","a85","a86","a87","a88","a89",\
  "a90","a91","a92","a93","a94","a95","a96","a97","a98","a99",\
  "a100","a101","a102","a103","a104","a105","a106","a107","a108","a109",\
  "a110","a111","a112","a113","a114","a115","a116","a117","a118","a119",\
  "a120","a121","a122","a123","a124","a125","a126","a127","a128","a129",\
  "a130","a131","a132","a133","a134","a135","a136","a137","a138","a139",\
  "a140","a141","a142","a143","a144","a145","a146","a147","a148","a149",\
  "a150","a151","a152","a153","a154","a155","a156","a157","a158","a159",\
  "a160","a161","a162","a163","a164","a165","a166","a167","a168","a169",\
  "a170","a171","a172","a173","a174","a175","a176","a177","a178","a179",\
  "a180","a181","a182","a183","a184","a185","a186","a187","a188","a189",\
  "a190","a191","a192","a193","a194","a195","a196","a197","a198","a199",\
  "a200","a201","a202","a203","a204","a205","a206","a207","a208","a209",\
  "a210","a211","a212","a213","a214","a215","a216","a217","a218","a219",\
  "a220","a221","a222","a223","a224","a225","a226","a227","a228","a229",\
  "a230","a231","a232","a233","a234","a235","a236","a237","a238","a239",\
  "a240","a241","a242","a243","a244","a245","a246","a247","a248","a249",\
  "a250","a251","a252","a253","a254","a255"

// load one 16B weight fragment and pin it into 4 NAMED AGPRs.
#define PINFRAG(off, A0, A1, A2, A3) do {                                   \
  int4 q_;                                                                  \
  asm volatile("global_load_dwordx4 %0, %1, off\n\ts_waitcnt vmcnt(0)"      \
               : "=v"(q_) : "v"(wpb + (off)));                              \
  asm volatile("v_accvgpr_write_b32 " A0 ", %0\n\t"                         \
               "v_accvgpr_write_b32 " A1 ", %1\n\t"                         \
               "v_accvgpr_write_b32 " A2 ", %2\n\t"                         \
               "v_accvgpr_write_b32 " A3 ", %3"                             \
               :: "v"(q_.x), "v"(q_.y), "v"(q_.z), "v"(q_.w)                \
               : A0, A1, A2, A3);                                           \
} while (0)

// MFMA with B operand in named AGPRs (text); carries full AGPR clobbers so
// the allocator never places compiler values into a0..a255.
#define MFMA1(acc, af, AB)                                                  \
  asm volatile("v_mfma_f32_16x16x32_bf16 %0, %1, " AB ", %0"                \
               : "+v"(acc) : "v"(af) : AGPR_CLOB)

// MFMA with B operand in VGPRs (n-gate weights from LDS); same clobbers.
#define MFMA1V(acc, af, bf)                                                 \
  asm volatile("v_mfma_f32_16x16x32_bf16 %0, %1, %2, %0"                    \
               : "+v"(acc) : "v"(af), "v"(bf) : AGPR_CLOB)

// ---------------------------------------------------------------------------
// K0: pack ALL W_hh gate rows into MFMA B-fragment stream layout (bf16)
// linear offset = (dir*8+w8)*24576 + g*8192 + tt*4096 + kk*512 + lane*8 + j
// ---------------------------------------------------------------------------
__global__ __launch_bounds__(1024) void pack_wh(
    const float* __restrict__ whf, const float* __restrict__ whb,
    unsigned short* __restrict__ wp)
{
  const int o = blockIdx.x * 1024 + threadIdx.x;   // 0..393215
  const int j    = o & 7;
  const int lane = (o >> 3) & 63;
  const int kk   = (o >> 9) & 7;
  const int tt   = (o >> 12) & 1;
  const int rest = o >> 13;
  const int g    = rest % 3;
  const int wv   = (rest / 3) & 7;
  const int dir  = rest / 24;
  const float* w = dir ? whb : whf;
  const int row = wv * 32 + tt * 16 + (lane & 15);
  const int k   = kk * 32 + (lane >> 4) * 8 + j;
  wp[o] = (unsigned short)f2bf(w[(size_t)(g * H_ + row) * H_ + k]);
}

// ---------------------------------------------------------------------------
// K1: xp = bf16( x @ w_ih^T + b_ih (+ b_hh for r,z) ), both dirs.
// Output layout: xp[t][grp=b/4][g][4]
// ---------------------------------------------------------------------------
__global__ __launch_bounds__(256) void xp_gemm_bf(
    const float* __restrict__ x,
    const float* __restrict__ wf, const float* __restrict__ wb,
    const float* __restrict__ bif, const float* __restrict__ bhf,
    const float* __restrict__ bib, const float* __restrict__ bhb,
    unsigned short* __restrict__ xpf, unsigned short* __restrict__ xpb)
{
  const int sb = blockIdx.x;
  const int bn = blockIdx.y;
  const bool fwd = (bn < 6);
  const float* __restrict__ wsrc = fwd ? wf : wb;
  const float* __restrict__ bi   = fwd ? bif : bib;
  const float* __restrict__ bh   = fwd ? bhf : bhb;
  const int nloc0 = (fwd ? bn : bn - 6) * 128;

  __shared__ __align__(16) unsigned short As[128][56];
  __shared__ __align__(16) unsigned short Bs[128][56];

  const int tid  = threadIdx.x;
  const int wave = tid >> 6, lane = tid & 63;
  const int col  = lane & 15, lg = lane >> 4;
  const int wm   = wave >> 1, wn = wave & 1;
  const int rr   = tid >> 1;
  const int hf   = (tid & 1) * 16;

  const float* ax = x    + ((size_t)(rr * 128 + sb) * IN_ + hf);
  const float* bx = wsrc + ((size_t)(nloc0 + rr) * IN_ + hf);

  f32x4 acc[4][4];
#pragma unroll
  for (int i = 0; i < 4; ++i)
#pragma unroll
    for (int j = 0; j < 4; ++j) acc[i][j] = f32x4{0.f, 0.f, 0.f, 0.f};

  for (int k0 = 0; k0 < IN_; k0 += 32) {
    float4 a0 = *(const float4*)(ax + k0);
    float4 a1 = *(const float4*)(ax + k0 + 4);
    float4 a2 = *(const float4*)(ax + k0 + 8);
    float4 a3 = *(const float4*)(ax + k0 + 12);
    float4 c0 = *(const float4*)(bx + k0);
    float4 c1 = *(const float4*)(bx + k0 + 4);
    float4 c2 = *(const float4*)(bx + k0 + 8);
    float4 c3 = *(const float4*)(bx + k0 + 12);
    __syncthreads();
    {
      bf16x8 p0, p1;
      p0[0]=f2bf(a0.x); p0[1]=f2bf(a0.y); p0[2]=f2bf(a0.z); p0[3]=f2bf(a0.w);
      p0[4]=f2bf(a1.x); p0[5]=f2bf(a1.y); p0[6]=f2bf(a1.z); p0[7]=f2bf(a1.w);
      p1[0]=f2bf(a2.x); p1[1]=f2bf(a2.y); p1[2]=f2bf(a2.z); p1[3]=f2bf(a2.w);
      p1[4]=f2bf(a3.x); p1[5]=f2bf(a3.y); p1[6]=f2bf(a3.z); p1[7]=f2bf(a3.w);
      *(bf16x8*)&As[rr][hf]     = p0;
      *(bf16x8*)&As[rr][hf + 8] = p1;
      p0[0]=f2bf(c0.x); p0[1]=f2bf(c0.y); p0[2]=f2bf(c0.z); p0[3]=f2bf(c0.w);
      p0[4]=f2bf(c1.x); p0[5]=f2bf(c1.y); p0[6]=f2bf(c1.z); p0[7]=f2bf(c1.w);
      p1[0]=f2bf(c2.x); p1[1]=f2bf(c2.y); p1[2]=f2bf(c2.z); p1[3]=f2bf(c2.w);
      p1[4]=f2bf(c3.x); p1[5]=f2bf(c3.y); p1[6]=f2bf(c3.z); p1[7]=f2bf(c3.w);
      *(bf16x8*)&Bs[rr][hf]     = p0;
      *(bf16x8*)&Bs[rr][hf + 8] = p1;
    }
    __syncthreads();
    bf16x8 af[4], bfv[4];
#pragma unroll
    for (int mi = 0; mi < 4; ++mi)
      af[mi] = *(const bf16x8*)&As[wm * 64 + mi * 16 + col][lg * 8];
#pragma unroll
    for (int ni = 0; ni < 4; ++ni)
      bfv[ni] = *(const bf16x8*)&Bs[wn * 64 + ni * 16 + col][lg * 8];
#pragma unroll
    for (int mi = 0; mi < 4; ++mi)
#pragma unroll
      for (int ni = 0; ni < 4; ++ni)
        acc[mi][ni] = __builtin_amdgcn_mfma_f32_16x16x32_bf16(af[mi], bfv[ni], acc[mi][ni], 0, 0, 0);
  }

  const int t = fwd ? sb : (S_ - 1 - sb);
  unsigned short* __restrict__ dstbase = fwd ? xpf : xpb;
#pragma unroll
  for (int ni = 0; ni < 4; ++ni) {
    const int g = nloc0 + wn * 64 + ni * 16 + col;
    const float bias = bi[g] + (g < 2 * H_ ? bh[g] : 0.f);
#pragma unroll
    for (int mi = 0; mi < 4; ++mi) {
      const int grp = wm * 16 + mi * 4 + lg;             // b/4
      ushort4 o;
      o.x = (unsigned short)f2bf(acc[mi][ni][0] + bias);
      o.y = (unsigned short)f2bf(acc[mi][ni][1] + bias);
      o.z = (unsigned short)f2bf(acc[mi][ni][2] + bias);
      o.w = (unsigned short)f2bf(acc[mi][ni][3] + bias);
      *(ushort4*)(dstbase + (((size_t)t * 32 + grp) * G3_ + g) * 4) = o;
    }
  }
}

// ---------------------------------------------------------------------------
// K2: GRU recurrence. 64 blocks = 2 dirs x 32 groups of 4 batches.
// 256 threads = 4 waves (1 wave/SIMD -> 512-reg unified budget/wave).
// Each wave owns 64 units (4 tiles): r,z weights pinned in a0..a255 (named
// AGPRs; EVERY in-loop MFMA asm carries the a0..a255 clobber list so the
// allocator can never place compiler values there); n-gate weights resident
// in LDS (128KB, loaded once). Zero per-step weight streaming.
// ---------------------------------------------------------------------------
__global__ __launch_bounds__(256) void gru_mfma(
    const unsigned short* __restrict__ xpf, const unsigned short* __restrict__ xpb,
    const unsigned short* __restrict__ wp,
    const float* __restrict__ bhf, const float* __restrict__ bhb,
    const int* __restrict__ lens, float* __restrict__ out)
{
  const int dir  = blockIdx.x >> 5;
  const int grpb = blockIdx.x & 31;
  const int b0   = grpb * 4;
  const unsigned short* __restrict__ xp = dir ? xpb : xpf;
  const float* __restrict__ bhh = dir ? bhb : bhf;

  const int tid  = threadIdx.x;
  const int wave = tid >> 6;          // 0..3
  const int lane = tid & 63;
  const int col  = lane & 15;
  const int lg   = lane >> 4;
  const int ub   = wave * 64 + col;   // unit for tq=0; tq adds 16

  __shared__ __align__(16) unsigned short hlds[2][32][16][8];   // 16KB
  __shared__ __align__(16) unsigned short xlds[2][G3_ * 4];     // 12KB
  __shared__ __align__(16) unsigned short nlds[65536];          // 128KB n-gate W

  // zero BOTH h buffers (rows 4-15 must stay zero forever): 1024 int4
#pragma unroll
  for (int k = 0; k < 4; ++k)
    ((int4*)hlds)[k * 256 + tid] = int4{0, 0, 0, 0};

  // ---- pin r,z weight fragments into a0..a255 (once) ----
  const unsigned short* wpb = wp + (size_t)(dir * 8 + 2 * wave) * 24576 + lane * 8;
  // r tq0 (w8=2w,tt0,g0): a0-a31
  PINFRAG(0,     "a0","a1","a2","a3");     PINFRAG(512,   "a4","a5","a6","a7");
  PINFRAG(1024,  "a8","a9","a10","a11");   PINFRAG(1536,  "a12","a13","a14","a15");
  PINFRAG(2048,  "a16","a17","a18","a19"); PINFRAG(2560,  "a20","a21","a22","a23");
  PINFRAG(3072,  "a24","a25","a26","a27"); PINFRAG(3584,  "a28","a29","a30","a31");
  // r tq1 (w8=2w,tt1,g0): a32-a63
  PINFRAG(4096,  "a32","a33","a34","a35"); PINFRAG(4608,  "a36","a37","a38","a39");
  PINFRAG(5120,  "a40","a41","a42","a43"); PINFRAG(5632,  "a44","a45","a46","a47");
  PINFRAG(6144,  "a48","a49","a50","a51"); PINFRAG(6656,  "a52","a53","a54","a55");
  PINFRAG(7168,  "a56","a57","a58","a59"); PINFRAG(7680,  "a60","a61","a62","a63");
  // r tq2 (w8=2w+1,tt0,g0): a64-a95
  PINFRAG(24576, "a64","a65","a66","a67"); PINFRAG(25088, "a68","a69","a70","a71");
  PINFRAG(25600, "a72","a73","a74","a75"); PINFRAG(26112, "a76","a77","a78","a79");
  PINFRAG(26624, "a80","a81","a82","a83"); PINFRAG(27136, "a84","a85","a86","a87");
  PINFRAG(27648, "a88","a89","a90","a91"); PINFRAG(28160, "a92","a93","a94","a95");
  // r tq3 (w8=2w+1,tt1,g0): a96-a127
  PINFRAG(28672, "a96","a97","a98","a99");    PINFRAG(29184, "a100","a101","a102","a103");
  PINFRAG(29696, "a104","a105","a106","a107");PINFRAG(30208, "a108","a109","a110","a111");
  PINFRAG(30720, "a112","a113","a114","a115");PINFRAG(31232, "a116","a117","a118","a119");
  PINFRAG(31744, "a120","a121","a122","a123");PINFRAG(32256, "a124","a125","a126","a127");
  // z tq0 (w8=2w,tt0,g1): a128-a159
  PINFRAG(8192,  "a128","a129","a130","a131");PINFRAG(8704,  "a132","a133","a134","a135");
  PINFRAG(9216,  "a136","a137","a138","a139");PINFRAG(9728,  "a140","a141","a142","a143");
  PINFRAG(10240, "a144","a145","a146","a147");PINFRAG(10752, "a148","a149","a150","a151");
  PINFRAG(11264, "a152","a153","a154","a155");PINFRAG(11776, "a156","a157","a158","a159");
  // z tq1 (w8=2w,tt1,g1): a160-a191
  PINFRAG(12288, "a160","a161","a162","a163");PINFRAG(12800, "a164","a165","a166","a167");
  PINFRAG(13312, "a168","a169","a170","a171");PINFRAG(13824, "a172","a173","a174","a175");
  PINFRAG(14336, "a176","a177","a178","a179");PINFRAG(14848, "a180","a181","a182","a183");
  PINFRAG(15360, "a184","a185","a186","a187");PINFRAG(15872, "a188","a189","a190","a191");
  // z tq2 (w8=2w+1,tt0,g1): a192-a223
  PINFRAG(32768, "a192","a193","a194","a195");PINFRAG(33280, "a196","a197","a198","a199");
  PINFRAG(33792, "a200","a201","a202","a203");PINFRAG(34304, "a204","a205","a206","a207");
  PINFRAG(34816, "a208","a209","a210","a211");PINFRAG(35328, "a212","a213","a214","a215");
  PINFRAG(35840, "a216","a217","a218","a219");PINFRAG(36352, "a220","a221","a222","a223");
  // z tq3 (w8=2w+1,tt1,g1): a224-a255
  PINFRAG(36864, "a224","a225","a226","a227");PINFRAG(37376, "a228","a229","a230","a231");
  PINFRAG(37888, "a232","a233","a234","a235");PINFRAG(38400, "a236","a237","a238","a239");
  PINFRAG(38912, "a240","a241","a242","a243");PINFRAG(39424, "a244","a245","a246","a247");
  PINFRAG(39936, "a248","a249","a250","a251");PINFRAG(40448, "a252","a253","a254","a255");

  // ---- n-gate weights -> LDS (once). chunk c=(wt*4+tq)*8+kk, 1KB each ----
  for (int j = 0; j < 32; ++j) {
    const int c  = j * 4 + wave;                 // wave-uniform
    const int wt = c >> 5, tq = (c >> 3) & 3, kk = c & 7;
    const unsigned short* src = wp
        + (size_t)(dir * 8 + wt * 2 + (tq >> 1)) * 24576
        + 16384 + (tq & 1) * 4096 + kk * 512 + lane * 8;
    async16(src, (const char*)&nlds[0] + (size_t)c * 1024);
  }

  // stage t=0 (384 granules; 256 threads -> 2 passes)
  {
    const unsigned short* base = xp + (size_t)grpb * (G3_ * 4);
#pragma unroll
    for (int j = 0; j < 2; ++j) {
      const int c = j * 256 + tid;
      if (c < 384)
        async16(base + (size_t)c * 8,
                (const char*)&xlds[0][0] + (size_t)(j * 256 + wave * 64) * 16);
    }
  }

  float bhn[4];
#pragma unroll
  for (int tq = 0; tq < 4; ++tq) bhn[tq] = bhh[2 * H_ + ub + tq * 16];

  int len_[4];
#pragma unroll
  for (int i = 0; i < 4; ++i) len_[i] = lens[b0 + i];

  float hreg[4][4] = {};   // [tq][batch] -- tq index always a literal below

  const int s0 = dir ? (S_ - 1) : 0;
  float* op[4];
#pragma unroll
  for (int i = 0; i < 4; ++i)
    op[i] = out + ((size_t)(b0 + i) * S_ + s0) * D2H_ + dir * H_ + ub;
  const ptrdiff_t sdelta = dir ? -(ptrdiff_t)D2H_ : (ptrdiff_t)D2H_;

#define TQ_BODY(TQc, R0,R1,R2,R3,R4,R5,R6,R7, Z0,Z1,Z2,Z3,Z4,Z5,Z6,Z7)       \
  {                                                                           \
    const int u = ub + (TQc) * 16;                                            \
    const unsigned short* nb = &nlds[((wave * 4 + (TQc)) << 12) + lane * 8];  \
    bf16x8 nf0 = *(const bf16x8*)(nb);                                        \
    bf16x8 nf1 = *(const bf16x8*)(nb + 512);                                  \
    bf16x8 nf2 = *(const bf16x8*)(nb + 1024);                                 \
    bf16x8 nf3 = *(const bf16x8*)(nb + 1536);                                 \
    bf16x8 nf4 = *(const bf16x8*)(nb + 2048);                                 \
    bf16x8 nf5 = *(const bf16x8*)(nb + 2560);                                 \
    bf16x8 nf6 = *(const bf16x8*)(nb + 3072);                                 \
    bf16x8 nf7 = *(const bf16x8*)(nb + 3584);                                 \
    ushort4 r4 = *(const ushort4*)&xlds[xb][u * 4];                           \
    ushort4 z4 = *(const ushort4*)&xlds[xb][(H_ + u) * 4];                    \
    f32x4 accr, accz, accn;                                                   \
    accr[0]=bf2f(r4.x); accr[1]=bf2f(r4.y); accr[2]=bf2f(r4.z); accr[3]=bf2f(r4.w); \
    accz[0]=bf2f(z4.x); accz[1]=bf2f(z4.y); accz[2]=bf2f(z4.z); accz[3]=bf2f(z4.w); \
    accn = f32x4{bhn[TQc], bhn[TQc], bhn[TQc], bhn[TQc]};                     \
    asm volatile("s_nop 3" : "+v"(accr), "+v"(accz), "+v"(accn));             \
    MFMA1(accr, afr[0], R0); MFMA1(accz, afr[0], Z0); MFMA1V(accn, afr[0], nf0); \
    MFMA1(accr, afr[1], R1); MFMA1(accz, afr[1], Z1); MFMA1V(accn, afr[1], nf1); \
    MFMA1(accr, afr[2], R2); MFMA1(accz, afr[2], Z2); MFMA1V(accn, afr[2], nf2); \
    MFMA1(accr, afr[3], R3); MFMA1(accz, afr[3], Z3); MFMA1V(accn, afr[3], nf3); \
    MFMA1(accr, afr[4], R4); MFMA1(accz, afr[4], Z4); MFMA1V(accn, afr[4], nf4); \
    MFMA1(accr, afr[5], R5); MFMA1(accz, afr[5], Z5); MFMA1V(accn, afr[5], nf5); \
    MFMA1(accr, afr[6], R6); MFMA1(accz, afr[6], Z6); MFMA1V(accn, afr[6], nf6); \
    MFMA1(accr, afr[7], R7); MFMA1(accz, afr[7], Z7); MFMA1V(accn, afr[7], nf7); \
    asm volatile("s_nop 7\n\ts_nop 7\n\ts_nop 7"                              \
                 : "+v"(accr), "+v"(accz), "+v"(accn));                       \
    ushort4 n4 = *(const ushort4*)&xlds[xb][(2 * H_ + u) * 4];                \
    float hnv[4];                                                             \
    _Pragma("unroll")                                                         \
    for (int i = 0; i < 4; ++i) {                                             \
      float r  = 1.f / (1.f + __expf(-accr[i]));                              \
      float z  = 1.f / (1.f + __expf(-accz[i]));                              \
      float nx = bf2f((&n4.x)[i]) + r * accn[i];                              \
      float n  = 1.f - 2.f / (__expf(2.f * nx) + 1.f);                        \
      float hn = n + z * (hreg[TQc][i] - n);                                  \
      hreg[TQc][i] = hn;                                                      \
      hnv[i] = hn;                                                            \
    }                                                                         \
    if (lg == 0) {                                                            \
      unsigned pk01, pk23;                                                    \
      asm("v_cvt_pk_bf16_f32 %0, %1, %2" : "=v"(pk01) : "v"(hnv[0]), "v"(hnv[1])); \
      asm("v_cvt_pk_bf16_f32 %0, %1, %2" : "=v"(pk23) : "v"(hnv[2]), "v"(hnv[3])); \
      const int kb = u >> 3, jj = u & 7;                                      \
      hlds[p ^ 1][kb][0][jj] = (unsigned short)(pk01 & 0xffffu);              \
      hlds[p ^ 1][kb][1][jj] = (unsigned short)(pk01 >> 16);                  \
      hlds[p ^ 1][kb][2][jj] = (unsigned short)(pk23 & 0xffffu);              \
      hlds[p ^ 1][kb][3][jj] = (unsigned short)(pk23 >> 16);                  \
    }                                                                         \
  }

  int p = 0;
  for (int t = 0; t < S_; ++t) {
    __syncthreads();            // drains vmcnt: staging complete; hlds[p] visible
    const int xb = t & 1;

    // (1) deferred store of h(t-1)
    if (t > 0 && lg == 0) {
      const int s_prev = dir ? (S_ - t) : (t - 1);
#pragma unroll
      for (int i = 0; i < 4; ++i) {
        const bool m = s_prev < len_[i];
        op[i][0]  = m ? hreg[0][i] : 0.f;
        op[i][16] = m ? hreg[1][i] : 0.f;
        op[i][32] = m ? hreg[2][i] : 0.f;
        op[i][48] = m ? hreg[3][i] : 0.f;
        op[i] += sdelta;
      }
    }

    // (2) stage xp(t+1)
    if (t + 1 < S_) {
      const unsigned short* base = xp + ((size_t)(t + 1) * 32 + grpb) * (G3_ * 4);
#pragma unroll
      for (int j = 0; j < 2; ++j) {
        const int c = j * 256 + tid;
        if (c < 384)
          async16(base + (size_t)c * 8,
                  (const char*)&xlds[xb ^ 1][0] + (size_t)(j * 256 + wave * 64) * 16);
      }
    }

    // (3) hoist A (h) fragments once per step (tq-invariant)
    bf16x8 afr[8];
#pragma unroll
    for (int kk = 0; kk < 8; ++kk)
      afr[kk] = *(const bf16x8*)&hlds[p][kk * 4 + lg][col][0];

    TQ_BODY(0, "a[0:3]","a[4:7]","a[8:11]","a[12:15]","a[16:19]","a[20:23]","a[24:27]","a[28:31]",
               "a[128:131]","a[132:135]","a[136:139]","a[140:143]","a[144:147]","a[148:151]","a[152:155]","a[156:159]")
    TQ_BODY(1, "a[32:35]","a[36:39]","a[40:43]","a[44:47]","a[48:51]","a[52:55]","a[56:59]","a[60:63]",
               "a[160:163]","a[164:167]","a[168:171]","a[172:175]","a[176:179]","a[180:183]","a[184:187]","a[188:191]")
    TQ_BODY(2, "a[64:67]","a[68:71]","a[72:75]","a[76:79]","a[80:83]","a[84:87]","a[88:91]","a[92:95]",
               "a[192:195]","a[196:199]","a[200:203]","a[204:207]","a[208:211]","a[212:215]","a[216:219]","a[220:223]")
    TQ_BODY(3, "a[96:99]","a[100:103]","a[104:107]","a[108:111]","a[112:115]","a[116:119]","a[120:123]","a[124:127]",
               "a[224:227]","a[228:231]","a[232:235]","a[236:239]","a[240:243]","a[244:247]","a[248:251]","a[252:255]")

    p ^= 1;
  }
#undef TQ_BODY

  // epilogue: store h(127)
  if (lg == 0) {
    const int s_last = dir ? 0 : (S_ - 1);
#pragma unroll
    for (int i = 0; i < 4; ++i) {
      const bool m = s_last < len_[i];
      op[i][0]  = m ? hreg[0][i] : 0.f;
      op[i][16] = m ? hreg[1][i] : 0.f;
      op[i][32] = m ? hreg[2][i] : 0.f;
      op[i][48] = m ? hreg[3][i] : 0.f;
    }
  }
}

// ---------------------------------------------------------------------------
// K3: proj[b,s,c] = out[b,s,:] . proj_w[c,:] + proj_b[c]   (fp32)
// ---------------------------------------------------------------------------
__global__ __launch_bounds__(256) void proj_gemm(
    const float* __restrict__ a, const float* __restrict__ w,
    const float* __restrict__ bias, float* __restrict__ proj)
{
  const int bm = blockIdx.x;
  const int n0 = blockIdx.y * 64;

  __shared__ float As[16][68];
  __shared__ float Bs[16][68];

  const int tid = threadIdx.x;
  const int row = tid >> 2;
  const int kq  = (tid & 3) << 2;
  const int tx  = tid & 15, ty = tid >> 4;

  const float* arow = a + (size_t)(bm * 64 + row) * D2H_ + kq;
  const float* brow = w + (size_t)(n0 + row) * D2H_ + kq;

  float acc[4][4] = {};

  for (int k0 = 0; k0 < D2H_; k0 += 16) {
    float4 av = *(const float4*)(arow + k0);
    float4 bv = *(const float4*)(brow + k0);
    As[kq + 0][row] = av.x; As[kq + 1][row] = av.y;
    As[kq + 2][row] = av.z; As[kq + 3][row] = av.w;
    Bs[kq + 0][row] = bv.x; Bs[kq + 1][row] = bv.y;
    Bs[kq + 2][row] = bv.z; Bs[kq + 3][row] = bv.w;
    __syncthreads();
#pragma unroll
    for (int k = 0; k < 16; ++k) {
      float4 av2 = *(const float4*)&As[k][ty * 4];
      float4 bv2 = *(const float4*)&Bs[k][tx * 4];
      acc[0][0] += av2.x * bv2.x; acc[0][1] += av2.x * bv2.y; acc[0][2] += av2.x * bv2.z; acc[0][3] += av2.x * bv2.w;
      acc[1][0] += av2.y * bv2.x; acc[1][1] += av2.y * bv2.y; acc[1][2] += av2.y * bv2.z; acc[1][3] += av2.y * bv2.w;
      acc[2][0] += av2.z * bv2.x; acc[2][1] += av2.z * bv2.y; acc[2][2] += av2.z * bv2.z; acc[2][3] += av2.z * bv2.w;
      acc[3][0] += av2.w * bv2.x; acc[3][1] += av2.w * bv2.y; acc[3][2] += av2.w * bv2.z; acc[3][3] += av2.w * bv2.w;
    }
    __syncthreads();
  }

  float4 bv4 = *(const float4*)(bias + n0 + tx * 4);
#pragma unroll
  for (int i = 0; i < 4; ++i) {
    int m = bm * 64 + ty * 4 + i;
    float4 o;
    o.x = acc[i][0] + bv4.x; o.y = acc[i][1] + bv4.y;
    o.z = acc[i][2] + bv4.z; o.w = acc[i][3] + bv4.w;
    *(float4*)(proj + (size_t)m * C_ + n0 + tx * 4) = o;
  }
}

// ---------------------------------------------------------------------------
__global__ __launch_bounds__(256) void bn_stats(
    const float* __restrict__ proj, float* __restrict__ mu, float* __restrict__ rstd)
{
  const int s = blockIdx.x, tid = threadIdx.x;
  float sum = 0.f, sq = 0.f;
  for (int b = 0; b < B_; ++b) {
    float v = proj[((size_t)b * S_ + s) * C_ + tid];
    sum += v; sq += v * v;
  }
#pragma unroll
  for (int o = 32; o; o >>= 1) { sum += __shfl_down(sum, o); sq += __shfl_down(sq, o); }
  __shared__ float r1[4], r2[4];
  const int lane = tid & 63, wid = tid >> 6;
  if (!lane) { r1[wid] = sum; r2[wid] = sq; }
  __syncthreads();
  if (!tid) {
    float s1 = r1[0] + r1[1] + r1[2] + r1[3];
    float s2 = r2[0] + r2[1] + r2[2] + r2[3];
    float m = s1 / (float)(B_ * C_);
    float var = s2 / (float)(B_ * C_) - m * m;
    mu[s] = m;
    rstd[s] = rsqrtf(var + 1e-5f);
  }
}

__global__ __launch_bounds__(256) void score_k(
    const float* __restrict__ proj, const float* __restrict__ mu,
    const float* __restrict__ rstd, const float* __restrict__ gamma,
    const float* __restrict__ beta, const float* __restrict__ ctx,
    float* __restrict__ scores)
{
  const int wid = threadIdx.x >> 6, lane = threadIdx.x & 63;
  const int m = blockIdx.x * 4 + wid;
  const int s = m & 127;
  float4 v  = *(const float4*)(proj + (size_t)m * C_ + lane * 4);
  float4 cv = *(const float4*)(ctx + lane * 4);
  const float ms = mu[s], rs = rstd[s], g = gamma[s], be = beta[s];
  float acc = fmaxf((v.x - ms) * rs * g + be, 0.f) * cv.x
            + fmaxf((v.y - ms) * rs * g + be, 0.f) * cv.y
            + fmaxf((v.z - ms) * rs * g + be, 0.f) * cv.z
            + fmaxf((v.w - ms) * rs * g + be, 0.f) * cv.w;
#pragma unroll
  for (int o = 32; o; o >>= 1) acc += __shfl_down(acc, o);
  if (!lane) scores[m] = acc;
}

__global__ __launch_bounds__(128) void softmax_k(
    const float* __restrict__ scores, float* __restrict__ attn)
{
  const int b = blockIdx.x, tid = threadIdx.x;
  float v = scores[b * S_ + tid];
  float mx = v;
#pragma unroll
  for (int o = 32; o; o >>= 1) mx = fmaxf(mx, __shfl_down(mx, o));
  __shared__ float t0[2], t1[2];
  const int lane = tid & 63, wid = tid >> 6;
  if (!lane) t0[wid] = mx;
  __syncthreads();
  mx = fmaxf(t0[0], t0[1]);
  float e = __expf(v - mx);
  float ssum = e;
#pragma unroll
  for (int o = 32; o; o >>= 1) ssum += __shfl_down(ssum, o);
  if (!lane) t1[wid] = ssum;
  __syncthreads();
  attn[b * S_ + tid] = e / (t1[0] + t1[1]);
}

__global__ __launch_bounds__(512) void final_k(
    const float* __restrict__ attn, const float* __restrict__ out,
    float* __restrict__ y)
{
  const int b = blockIdx.x, d = threadIdx.x;
  __shared__ float a[S_];
  if (threadIdx.x < S_) a[threadIdx.x] = attn[b * S_ + threadIdx.x];
  __syncthreads();
  float acc = 0.f;
  for (int s = 0; s < S_; ++s)
    acc += a[s] * out[((size_t)b * S_ + s) * D2H_ + d];
  y[(size_t)b * D2H_ + d] = acc;
}

// ---------------------------------------------------------------------------
extern "C" void kernel_launch(void* const* d_in, const int* in_sizes, int n_in,
                              void* d_out, int out_size, void* d_ws, size_t ws_size,
                              hipStream_t stream)
{
  const float* x      = (const float*)d_in[0];
  const int*   lens   = (const int*)d_in[2];
  const float* w_ih_f = (const float*)d_in[3];
  const float* w_hh_f = (const float*)d_in[4];
  const float* b_ih_f = (const float*)d_in[5];
  const float* b_hh_f = (const float*)d_in[6];
  const float* w_ih_b = (const float*)d_in[7];
  const float* w_hh_b = (const float*)d_in[8];
  const float* b_ih_b = (const float*)d_in[9];
  const float* b_hh_b = (const float*)d_in[10];
  const float* proj_w = (const float*)d_in[11];
  const float* proj_b = (const float*)d_in[12];
  const float* gamma  = (const float*)d_in[13];
  const float* beta   = (const float*)d_in[14];
  const float* ctx    = (const float*)d_in[15];

  float* ws = (float*)d_ws;
  // outm 32MB | xpf 24MB | xpb 24MB | wp 768KB  (~81 MB)
  float* outm = ws;                                        //  8,388,608 f
  unsigned short* xpf = (unsigned short*)(ws + 8388608);   // 12,582,912 us
  unsigned short* xpb = xpf + 12582912;                    // 12,582,912 us
  unsigned short* wp  = xpb + 12582912;                    //    393,216 us
  // epilogue aliases (xp dead after gru):
  float* proj   = ws + 8388608;                            //  4,194,304 f
  float* mu     = ws + 12582912;
  float* rstd   = ws + 12583040;
  float* scores = ws + 12583168;
  float* attn   = ws + 12599552;

  pack_wh<<<384, 1024, 0, stream>>>(w_hh_f, w_hh_b, wp);
  xp_gemm_bf<<<dim3(128, 12), 256, 0, stream>>>(
      x, w_ih_f, w_ih_b, b_ih_f, b_hh_f, b_ih_b, b_hh_b, xpf, xpb);
  gru_mfma<<<64, 256, 0, stream>>>(xpf, xpb, wp, b_hh_f, b_hh_b, lens, outm);
  proj_gemm<<<dim3(256, 4), 256, 0, stream>>>(outm, proj_w, proj_b, proj);
  bn_stats<<<128, 256, 0, stream>>>(proj, mu, rstd);
  score_k<<<4096, 256, 0, stream>>>(proj, mu, rstd, gamma, beta, ctx, scores);
  softmax_k<<<128, 128, 0, stream>>>(scores, attn);
  final_k<<<128, 512, 0, stream>>>(attn, outm, (float*)d_out);
}